// Round 1
// baseline (267.333 us; speedup 1.0000x reference)
//
#include <hip/hip_runtime.h>

#define SEQ 2048
#define EMBED 1024
#define NHEADS 16
#define HD 64

typedef __attribute__((ext_vector_type(4))) float f32x4;
typedef __attribute__((ext_vector_type(8))) unsigned short u16x8;
typedef __attribute__((ext_vector_type(8))) __bf16 bf16x8;

// round-to-nearest-even f32 -> bf16 (bit trick)
static __device__ __forceinline__ unsigned short f2bf(float f) {
  unsigned u = __builtin_bit_cast(unsigned, f);
  return (unsigned short)((u + 0x7FFFu + ((u >> 16) & 1u)) >> 16);
}

static __device__ __forceinline__ f32x4 mfma16(u16x8 a, u16x8 b, f32x4 c) {
  return __builtin_amdgcn_mfma_f32_16x16x32_bf16(
      __builtin_bit_cast(bf16x8, a), __builtin_bit_cast(bf16x8, b), c, 0, 0, 0);
}

// ---------------------------------------------------------------------------
// Kernel 1: W_out f32 -> bf16
// ---------------------------------------------------------------------------
__global__ void convw(const float* __restrict__ W, unsigned short* __restrict__ Wb) {
  const int i = (blockIdx.x * 256 + threadIdx.x) * 4;
  f32x4 v = *(const f32x4*)(W + i);
  unsigned p0 = f2bf(v[0]) | ((unsigned)f2bf(v[1]) << 16);
  unsigned p1 = f2bf(v[2]) | ((unsigned)f2bf(v[3]) << 16);
  *(uint2*)&Wb[i] = make_uint2(p0, p1);
}

// ---------------------------------------------------------------------------
// Kernel 2: fused flash attention.
// Block = (n,h) x 64-query tile; 256 threads = 4 waves, 16 q-rows each.
// K tile [64k][64d] bf16 in LDS, XOR-swizzled (elem ^ ((row&7)<<3)).
// V tile stored TRANSPOSED [64d][64k] bf16, same swizzle -> PV B-frag is a
// straight ds_read_b128. P goes through per-wave LDS to convert the MFMA
// C-layout (row=4g+r,col=m) to A-layout (row=m, 8 contiguous k per lane).
// Output written bf16 to ws: attn[n*SEQ+q][h*64+d].
// ---------------------------------------------------------------------------
__global__ __launch_bounds__(256, 2) void attn_fused(
    const float* __restrict__ Vg, const float* __restrict__ Kg,
    const float* __restrict__ Qg, const int* __restrict__ maskg,
    unsigned short* __restrict__ attn_out)
{
  __shared__ __align__(16) unsigned short Ks[64 * 64];
  __shared__ __align__(16) unsigned short Vt[64 * 64];
  __shared__ __align__(16) unsigned short Ps[4][16 * 64];
  __shared__ float mbias[64];

  const int tid = threadIdx.x;
  const int w = tid >> 6;        // wave 0..3
  const int l = tid & 63;
  const int m = l & 15;          // MFMA col / A-row lane
  const int g = l >> 4;          // lane group 0..3
  const int qb = blockIdx.x;     // 0..31
  const int nh = blockIdx.y;     // 0..63
  const int n = nh >> 4;
  const int h = nh & 15;

  // --- load Q fragments for this wave's 16 rows (f32 -> bf16, in regs) ---
  u16x8 qf[2];
  {
    const float* qp = Qg + (size_t)(n * SEQ + qb * 64 + w * 16 + m) * EMBED + h * HD;
#pragma unroll
    for (int kc = 0; kc < 2; ++kc) {
      f32x4 a = *(const f32x4*)(qp + kc * 32 + g * 8);
      f32x4 b = *(const f32x4*)(qp + kc * 32 + g * 8 + 4);
      u16x8 f;
#pragma unroll
      for (int j = 0; j < 4; ++j) { f[j] = f2bf(a[j]); f[4 + j] = f2bf(b[j]); }
      qf[kc] = f;
    }
  }

  f32x4 o[4];
#pragma unroll
  for (int i = 0; i < 4; ++i) o[i] = (f32x4){0.f, 0.f, 0.f, 0.f};
  float mr[4] = {-1e30f, -1e30f, -1e30f, -1e30f};  // running max (per row 4g+r)
  float lr[4] = {0.f, 0.f, 0.f, 0.f};              // per-lane partial row sums

  const int kr0 = tid >> 4;        // 0..15
  const int dc0 = (tid & 15) * 4;  // 0..60

  for (int kb = 0; kb < SEQ / 64; ++kb) {
    __syncthreads();  // previous tile fully consumed
    if (tid < 64)
      mbias[tid] = maskg[n * SEQ + kb * 64 + tid] ? 0.f : -1e30f;
    // --- stage K tile (row-major, swizzled) ---
#pragma unroll
    for (int i = 0; i < 4; ++i) {
      const int kr = kr0 + i * 16;
      f32x4 kv = *(const f32x4*)(Kg + (size_t)(n * SEQ + kb * 64 + kr) * EMBED + h * HD + dc0);
      unsigned p0 = f2bf(kv[0]) | ((unsigned)f2bf(kv[1]) << 16);
      unsigned p1 = f2bf(kv[2]) | ((unsigned)f2bf(kv[3]) << 16);
      *(uint2*)&Ks[kr * 64 + (dc0 ^ ((kr & 7) << 3))] = make_uint2(p0, p1);
    }
    // --- stage V tile transposed: thread owns a 4k x 4d micro-tile ---
    {
      const int k0 = kr0 * 4;
      f32x4 vv[4];
#pragma unroll
      for (int i = 0; i < 4; ++i)
        vv[i] = *(const f32x4*)(Vg + (size_t)(n * SEQ + kb * 64 + k0 + i) * EMBED + h * HD + dc0);
#pragma unroll
      for (int j = 0; j < 4; ++j) {
        const int dr = dc0 + j;
        unsigned p0 = f2bf(vv[0][j]) | ((unsigned)f2bf(vv[1][j]) << 16);
        unsigned p1 = f2bf(vv[2][j]) | ((unsigned)f2bf(vv[3][j]) << 16);
        *(uint2*)&Vt[dr * 64 + (k0 ^ ((dr & 7) << 3))] = make_uint2(p0, p1);
      }
    }
    __syncthreads();

    // --- S = Q K^T : 4 kcol subtiles x 2 k-chunks ---
    f32x4 s[4];
#pragma unroll
    for (int kcol = 0; kcol < 4; ++kcol) {
      f32x4 acc = (f32x4){0.f, 0.f, 0.f, 0.f};
#pragma unroll
      for (int kc = 0; kc < 2; ++kc) {
        const int krow = kcol * 16 + m;
        u16x8 kf = *(const u16x8*)&Ks[krow * 64 + ((kc * 32 + g * 8) ^ ((krow & 7) << 3))];
        acc = mfma16(qf[kc], kf, acc);
      }
      s[kcol] = acc;
    }

    // --- online softmax (rows 4g+r live in this lane's group) ---
    float lg[4][4], tmax[4];
#pragma unroll
    for (int r = 0; r < 4; ++r) tmax[r] = -1e30f;
#pragma unroll
    for (int kcol = 0; kcol < 4; ++kcol) {
      const float bias = mbias[kcol * 16 + m];
#pragma unroll
      for (int r = 0; r < 4; ++r) {
        lg[kcol][r] = s[kcol][r] * 0.03125f + bias;  // /sqrt(1024)
        tmax[r] = fmaxf(tmax[r], lg[kcol][r]);
      }
    }
#pragma unroll
    for (int r = 0; r < 4; ++r) {
#pragma unroll
      for (int d = 1; d < 16; d <<= 1)
        tmax[r] = fmaxf(tmax[r], __shfl_xor(tmax[r], d));
      const float mn = fmaxf(mr[r], tmax[r]);
      const float corr = __expf(mr[r] - mn);
      mr[r] = mn;
      lr[r] *= corr;
#pragma unroll
      for (int dcol = 0; dcol < 4; ++dcol) o[dcol][r] *= corr;
    }
#pragma unroll
    for (int kcol = 0; kcol < 4; ++kcol) {
#pragma unroll
      for (int r = 0; r < 4; ++r) {
        const float p = (lg[kcol][r] < -1e29f) ? 0.f : __expf(lg[kcol][r] - mr[r]);
        lr[r] += p;
        const int pr = g * 4 + r;
        Ps[w][pr * 64 + ((kcol * 16 + m) ^ ((pr & 7) << 3))] = f2bf(p);
      }
    }

    // --- O += P V ---
#pragma unroll
    for (int kc = 0; kc < 2; ++kc) {
      u16x8 pf = *(const u16x8*)&Ps[w][m * 64 + ((kc * 32 + g * 8) ^ ((m & 7) << 3))];
#pragma unroll
      for (int dcol = 0; dcol < 4; ++dcol) {
        const int vr = dcol * 16 + m;
        u16x8 vf = *(const u16x8*)&Vt[vr * 64 + ((kc * 32 + g * 8) ^ ((vr & 7) << 3))];
        o[dcol] = mfma16(pf, vf, o[dcol]);
      }
    }
  }

  // --- finalize: reduce row sums across the 16-lane group, scale, store bf16 ---
  float inv[4];
#pragma unroll
  for (int r = 0; r < 4; ++r) {
#pragma unroll
    for (int d = 1; d < 16; d <<= 1) lr[r] += __shfl_xor(lr[r], d);
    inv[r] = 1.f / lr[r];
  }
  unsigned short* op =
      attn_out + (size_t)(n * SEQ + qb * 64 + w * 16 + g * 4) * EMBED + h * HD + m;
#pragma unroll
  for (int r = 0; r < 4; ++r)
#pragma unroll
    for (int dcol = 0; dcol < 4; ++dcol)
      op[(size_t)r * EMBED + dcol * 16] = f2bf(o[dcol][r] * inv[r]);
}

// ---------------------------------------------------------------------------
// Kernel 3: out[8192][1024] = attn_bf16 @ W_bf16^T + b  (f32 out)
// 128x128 tile, BK=64, 4 waves in 2x2, 4x4 16x16 frags per wave.
// Reg-staged swizzled LDS (single buffer, 2-barrier loop).
// ---------------------------------------------------------------------------
__global__ __launch_bounds__(256, 2) void proj_gemm(
    const unsigned short* __restrict__ A, const unsigned short* __restrict__ Bw,
    const float* __restrict__ bias, float* __restrict__ out)
{
  __shared__ __align__(16) unsigned short As[128 * 64];
  __shared__ __align__(16) unsigned short Bs[128 * 64];
  const int tid = threadIdx.x;
  const int l = tid & 63, m = l & 15, g = l >> 4;
  const int w = tid >> 6, wm = w >> 1, wn = w & 1;
  const int m0 = blockIdx.y * 128, n0 = blockIdx.x * 128;
  const int srow = tid >> 3, slot = tid & 7;

  f32x4 acc[4][4];
#pragma unroll
  for (int i = 0; i < 4; ++i)
#pragma unroll
    for (int j = 0; j < 4; ++j) acc[i][j] = (f32x4){0.f, 0.f, 0.f, 0.f};

  for (int kk = 0; kk < EMBED; kk += 64) {
    __syncthreads();
#pragma unroll
    for (int i = 0; i < 4; ++i) {
      const int row = i * 32 + srow;
      u16x8 va = *(const u16x8*)(A + (size_t)(m0 + row) * EMBED + kk + slot * 8);
      u16x8 vb = *(const u16x8*)(Bw + (size_t)(n0 + row) * EMBED + kk + slot * 8);
      const int soff = (slot * 8) ^ ((row & 7) << 3);
      *(u16x8*)&As[row * 64 + soff] = va;
      *(u16x8*)&Bs[row * 64 + soff] = vb;
    }
    __syncthreads();
#pragma unroll
    for (int kc = 0; kc < 2; ++kc) {
      u16x8 af[4], bf[4];
#pragma unroll
      for (int mi = 0; mi < 4; ++mi) {
        const int row = wm * 64 + mi * 16 + m;
        af[mi] = *(const u16x8*)&As[row * 64 + ((kc * 32 + g * 8) ^ ((row & 7) << 3))];
      }
#pragma unroll
      for (int ni = 0; ni < 4; ++ni) {
        const int row = wn * 64 + ni * 16 + m;
        bf[ni] = *(const u16x8*)&Bs[row * 64 + ((kc * 32 + g * 8) ^ ((row & 7) << 3))];
      }
#pragma unroll
      for (int mi = 0; mi < 4; ++mi)
#pragma unroll
        for (int ni = 0; ni < 4; ++ni)
          acc[mi][ni] = mfma16(af[mi], bf[ni], acc[mi][ni]);
    }
  }

#pragma unroll
  for (int ni = 0; ni < 4; ++ni) {
    const int col = n0 + wn * 64 + ni * 16 + m;
    const float bv = bias[col];
#pragma unroll
    for (int mi = 0; mi < 4; ++mi) {
      const int rb = m0 + wm * 64 + mi * 16 + g * 4;
#pragma unroll
      for (int r = 0; r < 4; ++r)
        out[(size_t)(rb + r) * EMBED + col] = acc[mi][ni][r] + bv;
    }
  }
}

// ---------------------------------------------------------------------------
extern "C" void kernel_launch(void* const* d_in, const int* in_sizes, int n_in,
                              void* d_out, int out_size, void* d_ws, size_t ws_size,
                              hipStream_t stream) {
  const float* Vg = (const float*)d_in[0];
  const float* Kg = (const float*)d_in[1];
  const float* Qg = (const float*)d_in[2];
  const int* maskg = (const int*)d_in[3];
  const float* Wg = (const float*)d_in[4];
  const float* bg = (const float*)d_in[5];

  unsigned short* attn = (unsigned short*)d_ws;                   // 8192x1024 bf16 = 16 MB
  unsigned short* Wb = attn + (size_t)4 * SEQ * EMBED;            // 1024x1024 bf16 = 2 MB
  float* out = (float*)d_out;

  convw<<<dim3(EMBED * EMBED / 1024), 256, 0, stream>>>(Wg, Wb);
  attn_fused<<<dim3(SEQ / 64, 4 * NHEADS), 256, 0, stream>>>(Vg, Kg, Qg, maskg, attn);
  proj_gemm<<<dim3(EMBED / 128, 4 * SEQ / 128), 256, 0, stream>>>(attn, Wb, bg, out);
}

// Round 2
// 194.907 us; speedup vs baseline: 1.3716x; 1.3716x over previous
//
#include <hip/hip_runtime.h>

#define SEQ 2048
#define EMBED 1024
#define NHEADS 16
#define HD 64

typedef __attribute__((ext_vector_type(4))) float f32x4;
typedef __attribute__((ext_vector_type(8))) unsigned short u16x8;
typedef __attribute__((ext_vector_type(8))) __bf16 bf16x8;

// round-to-nearest-even f32 -> bf16 (bit trick)
static __device__ __forceinline__ unsigned short f2bf(float f) {
  unsigned u = __builtin_bit_cast(unsigned, f);
  return (unsigned short)((u + 0x7FFFu + ((u >> 16) & 1u)) >> 16);
}

// packed f32x2 -> bf16x2 (lo = a, hi = b), RNE
static __device__ __forceinline__ unsigned cvtpk(float a, float b) {
  unsigned r;
  asm("v_cvt_pk_bf16_f32 %0, %1, %2" : "=v"(r) : "v"(a), "v"(b));
  return r;
}

static __device__ __forceinline__ f32x4 mfma16(u16x8 a, u16x8 b, f32x4 c) {
  return __builtin_amdgcn_mfma_f32_16x16x32_bf16(
      __builtin_bit_cast(bf16x8, a), __builtin_bit_cast(bf16x8, b), c, 0, 0, 0);
}

static __device__ __forceinline__ void gload_lds16(const void* g, void* l) {
  __builtin_amdgcn_global_load_lds(
      (const __attribute__((address_space(1))) unsigned*)g,
      (__attribute__((address_space(3))) unsigned*)l, 16, 0, 0);
}

// ---------------------------------------------------------------------------
// Kernel 1: W_out f32 -> bf16
// ---------------------------------------------------------------------------
__global__ void convw(const float* __restrict__ W, unsigned short* __restrict__ Wb) {
  const int i = (blockIdx.x * 256 + threadIdx.x) * 4;
  f32x4 v = *(const f32x4*)(W + i);
  *(uint2*)&Wb[i] = make_uint2(cvtpk(v[0], v[1]), cvtpk(v[2], v[3]));
}

// ---------------------------------------------------------------------------
// Kernel 2: K f32 [n][s][h*64+d] -> bf16 tiles [nh][kb][kr*64 + (dc ^ ((kr&7)<<3))]
// One block per (kb, nh) tile of 64x64.
// ---------------------------------------------------------------------------
__global__ __launch_bounds__(256) void convk(const float* __restrict__ Kg,
                                             unsigned short* __restrict__ Kb) {
  const int t = threadIdx.x;
  const int kb = blockIdx.x, nh = blockIdx.y;
  const int n = nh >> 4, h = nh & 15;
  const int kr = t >> 2;
  const int dc = (t & 3) * 16;
  const float* src = Kg + (size_t)(n * SEQ + kb * 64 + kr) * EMBED + h * HD + dc;
  f32x4 a = *(const f32x4*)(src);
  f32x4 b = *(const f32x4*)(src + 4);
  f32x4 c = *(const f32x4*)(src + 8);
  f32x4 d = *(const f32x4*)(src + 12);
  const int swz = (kr & 7) << 3;
  unsigned short* dst = Kb + ((size_t)nh * 32 + kb) * 4096 + kr * 64;
  *(uint4*)&dst[dc ^ swz] =
      make_uint4(cvtpk(a[0], a[1]), cvtpk(a[2], a[3]), cvtpk(b[0], b[1]), cvtpk(b[2], b[3]));
  *(uint4*)&dst[(dc + 8) ^ swz] =
      make_uint4(cvtpk(c[0], c[1]), cvtpk(c[2], c[3]), cvtpk(d[0], d[1]), cvtpk(d[2], d[3]));
}

// ---------------------------------------------------------------------------
// Kernel 3: V f32 -> bf16 transposed+permuted tiles:
//   Vt[nh][kb][d*64 + (pi(kl) ^ ((d&7)<<3))], pi(k) = (k&15)*4 + (k>>4)
// Thread (kq, dq): reads rows k = kq + 16*kcol, cols d0..d0+3 -> per d a
// contiguous 4-elem p-block at p0 = kq*4.
// ---------------------------------------------------------------------------
__global__ __launch_bounds__(256) void convv(const float* __restrict__ Vg,
                                             unsigned short* __restrict__ Vt) {
  const int t = threadIdx.x;
  const int kb = blockIdx.x, nh = blockIdx.y;
  const int n = nh >> 4, h = nh & 15;
  const int kq = t & 15, dq = t >> 4;
  const int d0 = dq * 4;
  f32x4 vv[4];
#pragma unroll
  for (int kcol = 0; kcol < 4; ++kcol)
    vv[kcol] = *(const f32x4*)(Vg + (size_t)(n * SEQ + kb * 64 + kq + 16 * kcol) * EMBED +
                               h * HD + d0);
  unsigned short* dst = Vt + ((size_t)nh * 32 + kb) * 4096;
#pragma unroll
  for (int dj = 0; dj < 4; ++dj) {
    const int d = d0 + dj;
    *(uint2*)&dst[d * 64 + ((kq * 4) ^ ((d & 7) << 3))] =
        make_uint2(cvtpk(vv[0][dj], vv[1][dj]), cvtpk(vv[2][dj], vv[3][dj]));
  }
}

// ---------------------------------------------------------------------------
// Kernel 4: fused flash attention, staging via global_load_lds (zero VALU).
// Block = (n,h) x 64-query tile; 256 threads = 4 waves, 16 q-rows each.
// K/Vt tiles are pre-swizzled in global, copied linearly to LDS (8 KB each).
// P stored pi-permuted: lane writes its 4 contiguous bf16 via cvt_pk + b64.
// ---------------------------------------------------------------------------
__global__ __launch_bounds__(256, 4) void attn_fused(
    const unsigned short* __restrict__ Kb, const unsigned short* __restrict__ Vtb,
    const float* __restrict__ Qg, const int* __restrict__ maskg,
    unsigned short* __restrict__ attn_out)
{
  __shared__ __align__(16) unsigned short Ks[64 * 64];
  __shared__ __align__(16) unsigned short Vt[64 * 64];
  __shared__ __align__(16) unsigned short Ps[4][16 * 64];
  __shared__ float mbias[64];

  const int tid = threadIdx.x;
  const int w = tid >> 6;        // wave 0..3
  const int l = tid & 63;
  const int m = l & 15;
  const int g = l >> 4;
  const int qb = blockIdx.x;     // 0..31
  const int nh = blockIdx.y;     // 0..63
  const int n = nh >> 4;
  const int h = nh & 15;

  // --- load Q fragments for this wave's 16 rows (f32 -> bf16, once) ---
  u16x8 qf[2];
  {
    const float* qp = Qg + (size_t)(n * SEQ + qb * 64 + w * 16 + m) * EMBED + h * HD;
#pragma unroll
    for (int kc = 0; kc < 2; ++kc) {
      f32x4 a = *(const f32x4*)(qp + kc * 32 + g * 8);
      f32x4 b = *(const f32x4*)(qp + kc * 32 + g * 8 + 4);
      u16x8 f;
#pragma unroll
      for (int j = 0; j < 4; ++j) { f[j] = f2bf(a[j]); f[4 + j] = f2bf(b[j]); }
      qf[kc] = f;
    }
  }

  f32x4 o[4];
#pragma unroll
  for (int i = 0; i < 4; ++i) o[i] = (f32x4){0.f, 0.f, 0.f, 0.f};
  float mr[4] = {-1e30f, -1e30f, -1e30f, -1e30f};
  float lr[4] = {0.f, 0.f, 0.f, 0.f};

  // staging source pointers (tiles are contiguous 4096 u16 per kb)
  const unsigned short* ksrc = Kb + (size_t)nh * 32 * 4096 + tid * 8;
  const unsigned short* vsrc = Vtb + (size_t)nh * 32 * 4096 + tid * 8;
  unsigned short* kdst = &Ks[w * 512];
  unsigned short* vdst = &Vt[w * 512];

  for (int kb = 0; kb < SEQ / 64; ++kb) {
    __syncthreads();  // previous tile fully consumed
    gload_lds16(ksrc, kdst);
    gload_lds16(ksrc + 2048, kdst + 2048);
    gload_lds16(vsrc, vdst);
    gload_lds16(vsrc + 2048, vdst + 2048);
    ksrc += 4096; vsrc += 4096;
    if (tid < 64)
      mbias[tid] = maskg[n * SEQ + kb * 64 + tid] ? 0.f : -1e30f;
    __syncthreads();  // staged data + mbias visible

    // --- S = Q K^T ---
    f32x4 s[4];
    __builtin_amdgcn_s_setprio(1);
#pragma unroll
    for (int kcol = 0; kcol < 4; ++kcol) {
      f32x4 acc = (f32x4){0.f, 0.f, 0.f, 0.f};
#pragma unroll
      for (int kc = 0; kc < 2; ++kc) {
        const int krow = kcol * 16 + m;
        u16x8 kf = *(const u16x8*)&Ks[krow * 64 + ((kc * 32 + g * 8) ^ ((krow & 7) << 3))];
        acc = mfma16(qf[kc], kf, acc);
      }
      s[kcol] = acc;
    }
    __builtin_amdgcn_s_setprio(0);

    // --- online softmax (rows g*4+r), defer-max THR=8 ---
    float lg[4][4], tmax[4];
#pragma unroll
    for (int r = 0; r < 4; ++r) tmax[r] = -1e30f;
#pragma unroll
    for (int kcol = 0; kcol < 4; ++kcol) {
      const float bias = mbias[kcol * 16 + m];
#pragma unroll
      for (int r = 0; r < 4; ++r) {
        lg[kcol][r] = s[kcol][r] * 0.03125f + bias;
        tmax[r] = fmaxf(tmax[r], lg[kcol][r]);
      }
    }
#pragma unroll
    for (int r = 0; r < 4; ++r) {
#pragma unroll
      for (int d = 1; d < 16; d <<= 1)
        tmax[r] = fmaxf(tmax[r], __shfl_xor(tmax[r], d));
    }
    int grow = 0;
#pragma unroll
    for (int r = 0; r < 4; ++r) grow |= (tmax[r] > mr[r] + 8.f) ? 1 : 0;
    if (__any(grow)) {
#pragma unroll
      for (int r = 0; r < 4; ++r) {
        const float mn = fmaxf(mr[r], tmax[r]);
        const float corr = __expf(mr[r] - mn);
        mr[r] = mn;
        lr[r] *= corr;
#pragma unroll
        for (int dcol = 0; dcol < 4; ++dcol) o[dcol][r] *= corr;
      }
    }
    // P = exp(lg - mr); store pi-permuted: lane's 4 values are contiguous
#pragma unroll
    for (int r = 0; r < 4; ++r) {
      float p0 = __expf(lg[0][r] - mr[r]);
      float p1 = __expf(lg[1][r] - mr[r]);
      float p2 = __expf(lg[2][r] - mr[r]);
      float p3 = __expf(lg[3][r] - mr[r]);
      lr[r] += (p0 + p1) + (p2 + p3);
      const int pr = g * 4 + r;
      *(uint2*)&Ps[w][pr * 64 + ((m * 4) ^ ((pr & 7) << 3))] =
          make_uint2(cvtpk(p0, p1), cvtpk(p2, p3));
    }

    // --- O += P V ---
    __builtin_amdgcn_s_setprio(1);
#pragma unroll
    for (int kc = 0; kc < 2; ++kc) {
      u16x8 pf = *(const u16x8*)&Ps[w][m * 64 + ((kc * 32 + g * 8) ^ ((m & 7) << 3))];
#pragma unroll
      for (int dcol = 0; dcol < 4; ++dcol) {
        const int vr = dcol * 16 + m;
        u16x8 vf = *(const u16x8*)&Vt[vr * 64 + ((kc * 32 + g * 8) ^ ((vr & 7) << 3))];
        o[dcol] = mfma16(pf, vf, o[dcol]);
      }
    }
    __builtin_amdgcn_s_setprio(0);
  }

  // --- finalize ---
  float inv[4];
#pragma unroll
  for (int r = 0; r < 4; ++r) {
#pragma unroll
    for (int d = 1; d < 16; d <<= 1) lr[r] += __shfl_xor(lr[r], d);
    inv[r] = 1.f / lr[r];
  }
  unsigned short* op =
      attn_out + (size_t)(n * SEQ + qb * 64 + w * 16 + g * 4) * EMBED + h * HD + m;
#pragma unroll
  for (int r = 0; r < 4; ++r)
#pragma unroll
    for (int dcol = 0; dcol < 4; ++dcol)
      op[(size_t)r * EMBED + dcol * 16] = f2bf(o[dcol][r] * inv[r]);
}

// ---------------------------------------------------------------------------
// Kernel 5: out[8192][1024] = attn_bf16 @ W_bf16^T + b  (f32 out)
// ---------------------------------------------------------------------------
__global__ __launch_bounds__(256, 2) void proj_gemm(
    const unsigned short* __restrict__ A, const unsigned short* __restrict__ Bw,
    const float* __restrict__ bias, float* __restrict__ out)
{
  __shared__ __align__(16) unsigned short As[128 * 64];
  __shared__ __align__(16) unsigned short Bs[128 * 64];
  const int tid = threadIdx.x;
  const int l = tid & 63, m = l & 15, g = l >> 4;
  const int w = tid >> 6, wm = w >> 1, wn = w & 1;
  const int m0 = blockIdx.y * 128, n0 = blockIdx.x * 128;
  const int srow = tid >> 3, slot = tid & 7;

  f32x4 acc[4][4];
#pragma unroll
  for (int i = 0; i < 4; ++i)
#pragma unroll
    for (int j = 0; j < 4; ++j) acc[i][j] = (f32x4){0.f, 0.f, 0.f, 0.f};

  for (int kk = 0; kk < EMBED; kk += 64) {
    __syncthreads();
#pragma unroll
    for (int i = 0; i < 4; ++i) {
      const int row = i * 32 + srow;
      u16x8 va = *(const u16x8*)(A + (size_t)(m0 + row) * EMBED + kk + slot * 8);
      u16x8 vb = *(const u16x8*)(Bw + (size_t)(n0 + row) * EMBED + kk + slot * 8);
      const int soff = (slot * 8) ^ ((row & 7) << 3);
      *(u16x8*)&As[row * 64 + soff] = va;
      *(u16x8*)&Bs[row * 64 + soff] = vb;
    }
    __syncthreads();
#pragma unroll
    for (int kc = 0; kc < 2; ++kc) {
      u16x8 af[4], bf[4];
#pragma unroll
      for (int mi = 0; mi < 4; ++mi) {
        const int row = wm * 64 + mi * 16 + m;
        af[mi] = *(const u16x8*)&As[row * 64 + ((kc * 32 + g * 8) ^ ((row & 7) << 3))];
      }
#pragma unroll
      for (int ni = 0; ni < 4; ++ni) {
        const int row = wn * 64 + ni * 16 + m;
        bf[ni] = *(const u16x8*)&Bs[row * 64 + ((kc * 32 + g * 8) ^ ((row & 7) << 3))];
      }
#pragma unroll
      for (int mi = 0; mi < 4; ++mi)
#pragma unroll
        for (int ni = 0; ni < 4; ++ni)
          acc[mi][ni] = mfma16(af[mi], bf[ni], acc[mi][ni]);
    }
  }

#pragma unroll
  for (int ni = 0; ni < 4; ++ni) {
    const int col = n0 + wn * 64 + ni * 16 + m;
    const float bv = bias[col];
#pragma unroll
    for (int mi = 0; mi < 4; ++mi) {
      const int rb = m0 + wm * 64 + mi * 16 + g * 4;
#pragma unroll
      for (int r = 0; r < 4; ++r)
        out[(size_t)(rb + r) * EMBED + col] = acc[mi][ni][r] + bv;
    }
  }
}

// ---------------------------------------------------------------------------
extern "C" void kernel_launch(void* const* d_in, const int* in_sizes, int n_in,
                              void* d_out, int out_size, void* d_ws, size_t ws_size,
                              hipStream_t stream) {
  const float* Vg = (const float*)d_in[0];
  const float* Kg = (const float*)d_in[1];
  const float* Qg = (const float*)d_in[2];
  const int* maskg = (const int*)d_in[3];
  const float* Wg = (const float*)d_in[4];
  const float* bg = (const float*)d_in[5];

  unsigned short* attn = (unsigned short*)d_ws;                 // 16 MB
  unsigned short* Wb = attn + (size_t)4 * SEQ * EMBED;          // 2 MB
  unsigned short* Kb = Wb + (size_t)EMBED * EMBED;              // 16 MB
  unsigned short* Vt = Kb + (size_t)4 * SEQ * EMBED;            // 16 MB
  float* out = (float*)d_out;

  convw<<<dim3(EMBED * EMBED / 1024), 256, 0, stream>>>(Wg, Wb);
  convk<<<dim3(SEQ / 64, 4 * NHEADS), 256, 0, stream>>>(Kg, Kb);
  convv<<<dim3(SEQ / 64, 4 * NHEADS), 256, 0, stream>>>(Vg, Vt);
  attn_fused<<<dim3(SEQ / 64, 4 * NHEADS), 256, 0, stream>>>(Kb, Vt, Qg, maskg, attn);
  proj_gemm<<<dim3(EMBED / 128, 4 * SEQ / 128), 256, 0, stream>>>(attn, Wb, bg, out);
}

// Round 3
// 175.783 us; speedup vs baseline: 1.5208x; 1.1088x over previous
//
#include <hip/hip_runtime.h>

#define SEQ 2048
#define EMBED 1024
#define NHEADS 16
#define HD 64

typedef __attribute__((ext_vector_type(4))) float f32x4;
typedef __attribute__((ext_vector_type(16))) float f32x16;
typedef __attribute__((ext_vector_type(8))) unsigned short u16x8;
typedef __attribute__((ext_vector_type(8))) __bf16 bf16x8;

// round-to-nearest-even f32 -> bf16 (bit trick)
static __device__ __forceinline__ unsigned short f2bf(float f) {
  unsigned u = __builtin_bit_cast(unsigned, f);
  return (unsigned short)((u + 0x7FFFu + ((u >> 16) & 1u)) >> 16);
}

// packed f32x2 -> bf16x2 (lo = a, hi = b), RNE
static __device__ __forceinline__ unsigned cvtpk(float a, float b) {
  unsigned r;
  asm("v_cvt_pk_bf16_f32 %0, %1, %2" : "=v"(r) : "v"(a), "v"(b));
  return r;
}

static __device__ __forceinline__ f32x4 mfma16(u16x8 a, u16x8 b, f32x4 c) {
  return __builtin_amdgcn_mfma_f32_16x16x32_bf16(
      __builtin_bit_cast(bf16x8, a), __builtin_bit_cast(bf16x8, b), c, 0, 0, 0);
}

static __device__ __forceinline__ f32x16 mfma32(u16x8 a, u16x8 b, f32x16 c) {
  return __builtin_amdgcn_mfma_f32_32x32x16_bf16(
      __builtin_bit_cast(bf16x8, a), __builtin_bit_cast(bf16x8, b), c, 0, 0, 0);
}

static __device__ __forceinline__ void gload_lds16(const void* g, void* l) {
  __builtin_amdgcn_global_load_lds(
      (const __attribute__((address_space(1))) unsigned*)g,
      (__attribute__((address_space(3))) unsigned*)l, 16, 0, 0);
}

static __device__ __forceinline__ f32x16 zero16() {
  f32x16 z;
#pragma unroll
  for (int i = 0; i < 16; ++i) z[i] = 0.f;
  return z;
}

// ---------------------------------------------------------------------------
// Kernel 1: W_out f32 -> bf16
// ---------------------------------------------------------------------------
__global__ void convw(const float* __restrict__ W, unsigned short* __restrict__ Wb) {
  const int i = (blockIdx.x * 256 + threadIdx.x) * 4;
  f32x4 v = *(const f32x4*)(W + i);
  *(uint2*)&Wb[i] = make_uint2(cvtpk(v[0], v[1]), cvtpk(v[2], v[3]));
}

// ---------------------------------------------------------------------------
// Kernel 2: K f32 [n][s][h*64+d] -> bf16 tiles [nh][kb][kr*64 + (dc ^ ((kr&7)<<3))]
// ---------------------------------------------------------------------------
__global__ __launch_bounds__(256) void convk(const float* __restrict__ Kg,
                                             unsigned short* __restrict__ Kb) {
  const int t = threadIdx.x;
  const int kb = blockIdx.x, nh = blockIdx.y;
  const int n = nh >> 4, h = nh & 15;
  const int kr = t >> 2;
  const int dc = (t & 3) * 16;
  const float* src = Kg + (size_t)(n * SEQ + kb * 64 + kr) * EMBED + h * HD + dc;
  f32x4 a = *(const f32x4*)(src);
  f32x4 b = *(const f32x4*)(src + 4);
  f32x4 c = *(const f32x4*)(src + 8);
  f32x4 d = *(const f32x4*)(src + 12);
  const int swz = (kr & 7) << 3;
  unsigned short* dst = Kb + ((size_t)nh * 32 + kb) * 4096 + kr * 64;
  *(uint4*)&dst[dc ^ swz] =
      make_uint4(cvtpk(a[0], a[1]), cvtpk(a[2], a[3]), cvtpk(b[0], b[1]), cvtpk(b[2], b[3]));
  *(uint4*)&dst[(dc + 8) ^ swz] =
      make_uint4(cvtpk(c[0], c[1]), cvtpk(c[2], c[3]), cvtpk(d[0], d[1]), cvtpk(d[2], d[3]));
}

// ---------------------------------------------------------------------------
// Kernel 3: V f32 -> bf16 plain-transposed tiles:
//   Vt[nh][kb][d*64 + (k ^ ((d&7)<<3))]
// Thread (kq = t>>4, dq = t&15): reads rows k = 4kq..4kq+3, cols d0..d0+3.
// ---------------------------------------------------------------------------
__global__ __launch_bounds__(256) void convv(const float* __restrict__ Vg,
                                             unsigned short* __restrict__ Vt) {
  const int t = threadIdx.x;
  const int kb = blockIdx.x, nh = blockIdx.y;
  const int n = nh >> 4, h = nh & 15;
  const int kq = t >> 4, dq = t & 15;
  const int d0 = dq * 4;
  f32x4 vv[4];
#pragma unroll
  for (int i = 0; i < 4; ++i)
    vv[i] = *(const f32x4*)(Vg + (size_t)(n * SEQ + kb * 64 + 4 * kq + i) * EMBED +
                            h * HD + d0);
  unsigned short* dst = Vt + ((size_t)nh * 32 + kb) * 4096;
#pragma unroll
  for (int dj = 0; dj < 4; ++dj) {
    const int d = d0 + dj;
    *(uint2*)&dst[d * 64 + ((4 * kq) ^ ((d & 7) << 3))] =
        make_uint2(cvtpk(vv[0][dj], vv[1][dj]), cvtpk(vv[2][dj], vv[3][dj]));
  }
}

// ---------------------------------------------------------------------------
// Kernel 4: fused flash attention, swapped-QK^T 32x32x16 structure.
// Block = (n,h) x 128-query tile; 4 waves x 32 q-rows. KVBLK = 64.
// S^T = mfma(K, Q^T): lane owns q = l&31; 32 P-values in-lane (2 subtiles).
// Softmax fully in-register (1 shfl_xor(32) for max). P -> bf16 via cvt_pk +
// v_permlane32_swap -> PV B-frags, O^T accumulated in C regs.
// K/V double-buffered via global_load_lds, 1 barrier per tile.
// Epilogue transposes O^T through LDS for coalesced bf16 stores.
// ---------------------------------------------------------------------------
__global__ __launch_bounds__(256, 3) void attn_fused(
    const unsigned short* __restrict__ Kb, const unsigned short* __restrict__ Vtb,
    const float* __restrict__ Qg, const int* __restrict__ maskg,
    unsigned short* __restrict__ attn_out)
{
  // [K0 | K1 | V0 | V1], 4096 u16 (8 KB) each = 32 KB total
  __shared__ __align__(16) unsigned short smem[16384];

  const int tid = threadIdx.x;
  const int w = tid >> 6;
  const int l = tid & 63;
  const int q = l & 31;    // this lane's q-row (within wave tile)
  const int hi = l >> 5;
  const int qb = blockIdx.x;   // 0..15
  const int nh = blockIdx.y;   // 0..63
  const int n = nh >> 4, h = nh & 15;

  // --- Q^T B-fragments: qf[ks] holds Q[qrow][d = 16ks + hi*8 + j] ---
  u16x8 qf[4];
  {
    const float* qp = Qg + (size_t)(n * SEQ + qb * 128 + w * 32 + q) * EMBED + h * HD + hi * 8;
#pragma unroll
    for (int ks = 0; ks < 4; ++ks) {
      f32x4 a = *(const f32x4*)(qp + ks * 16);
      f32x4 b = *(const f32x4*)(qp + ks * 16 + 4);
      u16x8 f;
#pragma unroll
      for (int j = 0; j < 4; ++j) { f[j] = f2bf(a[j]); f[4 + j] = f2bf(b[j]); }
      qf[ks] = f;
    }
  }

  f32x16 ot0 = zero16(), ot1 = zero16();  // O^T d-tiles 0 (d<32) and 1 (d>=32)
  float mr = -1e30f, lr = 0.f;            // running max (log2 units), denom

  const unsigned short* ksrc = Kb + (size_t)nh * 32 * 4096;
  const unsigned short* vsrc = Vtb + (size_t)nh * 32 * 4096;
  const int swzq = (q & 7) << 3;
  const float C = 0.04508422f;  // log2(e)/sqrt(1024)

  // prologue stage tile 0 into buf 0
  {
    const unsigned short* kg = ksrc + tid * 8;
    const unsigned short* vg = vsrc + tid * 8;
    gload_lds16(kg, &smem[tid * 8]); gload_lds16(kg + 2048, &smem[tid * 8 + 2048]);
    gload_lds16(vg, &smem[8192 + tid * 8]); gload_lds16(vg + 2048, &smem[8192 + tid * 8 + 2048]);
  }

  for (int kb = 0; kb < 32; ++kb) {
    const int buf = kb & 1;
    const int kbase = buf * 4096;
    const int vbase = 8192 + buf * 4096;
    int mv = maskg[n * SEQ + kb * 64 + l];
    __syncthreads();  // drains vmcnt: staged buf visible; prev other-buf reads done
    if (kb < 31) {
      const unsigned short* kg = ksrc + (size_t)(kb + 1) * 4096 + tid * 8;
      const unsigned short* vg = vsrc + (size_t)(kb + 1) * 4096 + tid * 8;
      const int ob = (buf ^ 1) * 4096;
      gload_lds16(kg, &smem[ob + tid * 8]);
      gload_lds16(kg + 2048, &smem[ob + tid * 8 + 2048]);
      gload_lds16(vg, &smem[8192 + ob + tid * 8]);
      gload_lds16(vg + 2048, &smem[8192 + ob + tid * 8 + 2048]);
    }
    const bool anym = __any(mv == 0);

    // --- S^T = K Q^T (two 32-k subtiles, 4 chained k-steps each) ---
    f32x16 s0 = zero16(), s1 = zero16();
    __builtin_amdgcn_s_setprio(1);
#pragma unroll
    for (int ks = 0; ks < 4; ++ks) {
      u16x8 k0 = *(const u16x8*)&smem[kbase + q * 64 + ((ks * 16 + hi * 8) ^ swzq)];
      s0 = mfma32(k0, qf[ks], s0);
      u16x8 k1 = *(const u16x8*)&smem[kbase + (32 + q) * 64 + ((ks * 16 + hi * 8) ^ swzq)];
      s1 = mfma32(k1, qf[ks], s1);
    }
    __builtin_amdgcn_s_setprio(0);

    // --- softmax in log2 domain, fully in-lane ---
    float lg[32];
#pragma unroll
    for (int r = 0; r < 16; ++r) { lg[r] = s0[r] * C; lg[16 + r] = s1[r] * C; }
    if (anym) {  // rare: apply mask bias per k
#pragma unroll
      for (int r = 0; r < 32; ++r) {
        const int r16 = r & 15;
        const int klocal = (r16 & 3) + 8 * (r16 >> 2) + 4 * hi + 32 * (r >> 4);
        lg[r] += maskg[n * SEQ + kb * 64 + klocal] ? 0.f : -1e5f;
      }
    }
    float tm = lg[0];
#pragma unroll
    for (int r = 1; r < 32; ++r) tm = fmaxf(tm, lg[r]);
    tm = fmaxf(tm, __shfl_xor(tm, 32));
    if (!__all(tm <= mr + 8.f)) {  // defer-max (T13)
      const float nm = fmaxf(mr, tm);
      const float corr = exp2f(mr - nm);
      mr = nm; lr *= corr;
#pragma unroll
      for (int r = 0; r < 16; ++r) { ot0[r] *= corr; ot1[r] *= corr; }
    }
    float ps0 = 0.f, ps1 = 0.f, ps2 = 0.f, ps3 = 0.f;
#pragma unroll
    for (int r = 0; r < 32; r += 4) {
      lg[r] = exp2f(lg[r] - mr);     ps0 += lg[r];
      lg[r + 1] = exp2f(lg[r + 1] - mr); ps1 += lg[r + 1];
      lg[r + 2] = exp2f(lg[r + 2] - mr); ps2 += lg[r + 2];
      lg[r + 3] = exp2f(lg[r + 3] - mr); ps3 += lg[r + 3];
    }
    lr += (ps0 + ps1) + (ps2 + ps3);

    // --- P -> bf16 B-frags (cvt_pk + permlane32_swap), O^T += V^T P^T ---
    __builtin_amdgcn_s_setprio(1);
#pragma unroll
    for (int s = 0; s < 2; ++s) {
#pragma unroll
      for (int c = 0; c < 2; ++c) {
        const float* p = &lg[s * 16 + 8 * c];
        unsigned L0 = cvtpk(p[0], p[1]);
        unsigned L1 = cvtpk(p[2], p[3]);
        unsigned M0 = cvtpk(p[4], p[5]);
        unsigned M1 = cvtpk(p[6], p[7]);
        asm volatile("v_permlane32_swap_b32 %0, %1" : "+v"(L0), "+v"(M0));
        asm volatile("v_permlane32_swap_b32 %0, %1" : "+v"(L1), "+v"(M1));
        const uint4 fr = make_uint4(L0, L1, M0, M1);
        const u16x8 pa = __builtin_bit_cast(u16x8, fr);
        const int ko = s * 32 + c * 16 + hi * 8;
        u16x8 v0 = *(const u16x8*)&smem[vbase + q * 64 + (ko ^ swzq)];
        ot0 = mfma32(v0, pa, ot0);
        u16x8 v1 = *(const u16x8*)&smem[vbase + (32 + q) * 64 + (ko ^ swzq)];
        ot1 = mfma32(v1, pa, ot1);
      }
    }
    __builtin_amdgcn_s_setprio(0);
  }

  // --- finalize: normalize, transpose O^T -> O rows via LDS, coalesced store ---
  lr += __shfl_xor(lr, 32);
  const float inv = 1.f / lr;
  __syncthreads();  // everyone done reading K/V LDS
  unsigned short* ep = &smem[w * 2304];  // 32 rows x 72 elems (pad vs bank conflicts)
#pragma unroll
  for (int u = 0; u < 4; ++u) {
    {
      const unsigned d0 = cvtpk(ot0[4 * u] * inv, ot0[4 * u + 1] * inv);
      const unsigned d1 = cvtpk(ot0[4 * u + 2] * inv, ot0[4 * u + 3] * inv);
      *(uint2*)&ep[q * 72 + 8 * u + 4 * hi] = make_uint2(d0, d1);
    }
    {
      const unsigned d0 = cvtpk(ot1[4 * u] * inv, ot1[4 * u + 1] * inv);
      const unsigned d1 = cvtpk(ot1[4 * u + 2] * inv, ot1[4 * u + 3] * inv);
      *(uint2*)&ep[q * 72 + 8 * u + 4 * hi + 32] = make_uint2(d0, d1);
    }
  }
  asm volatile("s_waitcnt lgkmcnt(0)" ::: "memory");
#pragma unroll
  for (int i = 0; i < 4; ++i) {
    const int q2 = i * 8 + (l >> 3);
    const uint4 vv = *(const uint4*)&ep[q2 * 72 + (l & 7) * 8];
    *(uint4*)&attn_out[(size_t)(n * SEQ + qb * 128 + w * 32 + q2) * EMBED + h * HD +
                       (l & 7) * 8] = vv;
  }
}

// ---------------------------------------------------------------------------
// Kernel 5: out[8192][1024] = attn_bf16 @ W_bf16^T + b  (f32 out)
// ---------------------------------------------------------------------------
__global__ __launch_bounds__(256, 2) void proj_gemm(
    const unsigned short* __restrict__ A, const unsigned short* __restrict__ Bw,
    const float* __restrict__ bias, float* __restrict__ out)
{
  __shared__ __align__(16) unsigned short As[128 * 64];
  __shared__ __align__(16) unsigned short Bs[128 * 64];
  const int tid = threadIdx.x;
  const int l = tid & 63, m = l & 15, g = l >> 4;
  const int w = tid >> 6, wm = w >> 1, wn = w & 1;
  const int m0 = blockIdx.y * 128, n0 = blockIdx.x * 128;
  const int srow = tid >> 3, slot = tid & 7;

  f32x4 acc[4][4];
#pragma unroll
  for (int i = 0; i < 4; ++i)
#pragma unroll
    for (int j = 0; j < 4; ++j) acc[i][j] = (f32x4){0.f, 0.f, 0.f, 0.f};

  for (int kk = 0; kk < EMBED; kk += 64) {
    __syncthreads();
#pragma unroll
    for (int i = 0; i < 4; ++i) {
      const int row = i * 32 + srow;
      u16x8 va = *(const u16x8*)(A + (size_t)(m0 + row) * EMBED + kk + slot * 8);
      u16x8 vb = *(const u16x8*)(Bw + (size_t)(n0 + row) * EMBED + kk + slot * 8);
      const int soff = (slot * 8) ^ ((row & 7) << 3);
      *(u16x8*)&As[row * 64 + soff] = va;
      *(u16x8*)&Bs[row * 64 + soff] = vb;
    }
    __syncthreads();
#pragma unroll
    for (int kc = 0; kc < 2; ++kc) {
      u16x8 af[4], bf[4];
#pragma unroll
      for (int mi = 0; mi < 4; ++mi) {
        const int row = wm * 64 + mi * 16 + m;
        af[mi] = *(const u16x8*)&As[row * 64 + ((kc * 32 + g * 8) ^ ((row & 7) << 3))];
      }
#pragma unroll
      for (int ni = 0; ni < 4; ++ni) {
        const int row = wn * 64 + ni * 16 + m;
        bf[ni] = *(const u16x8*)&Bs[row * 64 + ((kc * 32 + g * 8) ^ ((row & 7) << 3))];
      }
#pragma unroll
      for (int mi = 0; mi < 4; ++mi)
#pragma unroll
        for (int ni = 0; ni < 4; ++ni)
          acc[mi][ni] = mfma16(af[mi], bf[ni], acc[mi][ni]);
    }
  }

#pragma unroll
  for (int ni = 0; ni < 4; ++ni) {
    const int col = n0 + wn * 64 + ni * 16 + m;
    const float bv = bias[col];
#pragma unroll
    for (int mi = 0; mi < 4; ++mi) {
      const int rb = m0 + wm * 64 + mi * 16 + g * 4;
#pragma unroll
      for (int r = 0; r < 4; ++r)
        out[(size_t)(rb + r) * EMBED + col] = acc[mi][ni][r] + bv;
    }
  }
}

// ---------------------------------------------------------------------------
extern "C" void kernel_launch(void* const* d_in, const int* in_sizes, int n_in,
                              void* d_out, int out_size, void* d_ws, size_t ws_size,
                              hipStream_t stream) {
  const float* Vg = (const float*)d_in[0];
  const float* Kg = (const float*)d_in[1];
  const float* Qg = (const float*)d_in[2];
  const int* maskg = (const int*)d_in[3];
  const float* Wg = (const float*)d_in[4];
  const float* bg = (const float*)d_in[5];

  unsigned short* attn = (unsigned short*)d_ws;                 // 16 MB
  unsigned short* Wb = attn + (size_t)4 * SEQ * EMBED;          // 2 MB
  unsigned short* Kb = Wb + (size_t)EMBED * EMBED;              // 16 MB
  unsigned short* Vt = Kb + (size_t)4 * SEQ * EMBED;            // 16 MB
  float* out = (float*)d_out;

  convw<<<dim3(EMBED * EMBED / 1024), 256, 0, stream>>>(Wg, Wb);
  convk<<<dim3(SEQ / 64, 4 * NHEADS), 256, 0, stream>>>(Kg, Kb);
  convv<<<dim3(SEQ / 64, 4 * NHEADS), 256, 0, stream>>>(Vg, Vt);
  attn_fused<<<dim3(SEQ / 128, 4 * NHEADS), 256, 0, stream>>>(Kb, Vt, Qg, maskg, attn);
  proj_gemm<<<dim3(EMBED / 128, 4 * SEQ / 128), 256, 0, stream>>>(attn, Wb, bg, out);
}